// Round 1
// baseline (154.277 us; speedup 1.0000x reference)
//
#include <hip/hip_runtime.h>
#include <stdint.h>

// Spread 8 bits of a byte into 8 byte-lanes of a uint64.
// Lane k (byte k) gets bit (7-k) of b, as 0 or 1. No carries occur in the
// multiply because set-bit positions in the magic constant are 9 apart.
__device__ __forceinline__ uint64_t spread8(uint32_t b) {
    return (((uint64_t)b * 0x8040201008040201ULL) >> 7) & 0x0101010101010101ULL;
}

// Kernel 1: per byte-position bit counts over the vote axis + global popcount sum.
// Each thread owns 4 consecutive byte positions (int4 = 16B coalesced loads).
__global__ __launch_bounds__(256) void k_count(const int* __restrict__ flip,
                                               uint64_t* __restrict__ cnt,
                                               unsigned int* __restrict__ total,
                                               int npos, int nvotes) {
    int t = blockIdx.x * blockDim.x + threadIdx.x;
    int base = t * 4;
    if (base >= npos) return;
    const int4* fp = (const int4*)flip;
    int stride = npos >> 2;               // int4 stride between votes
    uint64_t c0 = 0, c1 = 0, c2 = 0, c3 = 0;
    unsigned int pop = 0;
    for (int v = 0; v < nvotes; ++v) {
        int4 x = fp[v * stride + t];
        uint32_t b0 = (uint32_t)x.x, b1 = (uint32_t)x.y,
                 b2 = (uint32_t)x.z, b3 = (uint32_t)x.w;
        c0 += spread8(b0);
        c1 += spread8(b1);
        c2 += spread8(b2);
        c3 += spread8(b3);
        pop += __popc(b0 | (b1 << 8) | (b2 << 16) | (b3 << 24));
    }
    ulonglong2* cp = (ulonglong2*)(cnt + base);   // 16B-aligned (32B per thread)
    cp[0] = make_ulonglong2(c0, c1);
    cp[1] = make_ulonglong2(c2, c3);
    // wave-64 reduction, then one atomic per wave (max vote sum = 134M < 2^32)
    for (int off = 32; off > 0; off >>= 1)
        pop += __shfl_down(pop, off, 64);
    if ((threadIdx.x & 63) == 0)
        atomicAdd(total, pop);
}

// Kernel 2: threshold, build mask, XNOR with weights, write floats, count mask bits.
__global__ __launch_bounds__(256) void k_apply(const int* __restrict__ weights,
                                               const uint64_t* __restrict__ cnt,
                                               const unsigned int* __restrict__ total,
                                               const float* __restrict__ vote_p_max,
                                               const int* __restrict__ n_votes_p,
                                               float* __restrict__ out,
                                               unsigned int* __restrict__ maskpop,
                                               int npos) {
    int t = blockIdx.x * blockDim.x + threadIdx.x;
    int base = t * 4;
    if (base >= npos) return;
    float nv = (float)n_votes_p[0];
    float mean = (float)((double)(*total) / ((double)npos * 8.0));
    float thresh = fmaxf(vote_p_max[0] * nv, mean);   // == max(p_max, mean/nv)*nv exactly
    const ulonglong2* cp = (const ulonglong2*)(cnt + base);
    ulonglong2 a = cp[0], b = cp[1];
    uint64_t cs[4] = {a.x, a.y, b.x, b.y};
    int4 w = ((const int4*)weights)[t];
    int wv[4] = {w.x, w.y, w.z, w.w};
    float o[4];
    unsigned int pop = 0;
#pragma unroll
    for (int j = 0; j < 4; ++j) {
        uint32_t mask = 0;
        uint64_t c = cs[j];
#pragma unroll
        for (int k = 0; k < 8; ++k) {
            uint32_t lane = (uint32_t)(c >> (8 * k)) & 0xFFu;  // count of bit (7-k)
            if ((float)lane > thresh) mask |= 1u << (7 - k);
        }
        pop += __popc(mask);
        o[j] = (float)((~(((uint32_t)wv[j]) ^ mask)) & 0xFFu);
    }
    ((float4*)out)[t] = make_float4(o[0], o[1], o[2], o[3]);
    for (int off = 32; off > 0; off >>= 1)
        pop += __shfl_down(pop, off, 64);
    if ((threadIdx.x & 63) == 0)
        atomicAdd(maskpop, pop);
}

__global__ void k_ratio(const unsigned int* __restrict__ maskpop,
                        float* __restrict__ out, int npos) {
    out[npos] = (float)((double)(*maskpop) / ((double)npos * 8.0));
}

extern "C" void kernel_launch(void* const* d_in, const int* in_sizes, int n_in,
                              void* d_out, int out_size, void* d_ws, size_t ws_size,
                              hipStream_t stream) {
    const int* weights     = (const int*)d_in[0];   // 2048*256 bytes, one per int32
    const int* flip        = (const int*)d_in[1];   // 32*2048*256, one byte per int32
    const int* n_votes_p   = (const int*)d_in[2];
    const float* vote_p_max = (const float*)d_in[3];

    int npos   = in_sizes[0];               // 524288 byte positions
    int nvotes = in_sizes[1] / in_sizes[0]; // 32

    // ws layout: [0..8) two uint32 counters (total, maskpop); [256..256+8*npos) counts
    unsigned int* counters = (unsigned int*)d_ws;
    uint64_t* cnt = (uint64_t*)((char*)d_ws + 256);
    hipMemsetAsync(d_ws, 0, 256, stream);   // ws is re-poisoned 0xAA before every call

    int nthreads = npos / 4;                // 131072
    int block = 256;
    int grid = (nthreads + block - 1) / block;  // 512

    k_count<<<grid, block, 0, stream>>>(flip, cnt, counters, npos, nvotes);
    k_apply<<<grid, block, 0, stream>>>(weights, cnt, counters, vote_p_max,
                                        n_votes_p, (float*)d_out, counters + 1, npos);
    k_ratio<<<1, 1, 0, stream>>>(counters + 1, (float*)d_out, npos);
}